// Round 3
// baseline (191.228 us; speedup 1.0000x reference)
//
#include <hip/hip_runtime.h>
#include <math.h>

#define B_N   8192
#define D_K   256
#define NGENE 200

typedef short  bf16x8 __attribute__((ext_vector_type(8)));
typedef float  f32x4  __attribute__((ext_vector_type(4)));

// ---- workspace layout (bytes) ----
#define OFF_FNBF    0u          // 8192*256*2 = 4194304
#define OFF_LPART   4194304u    // 16*8192*4  = 524288
#define OFF_LSE     4718592u    // 8192*4 = 32768
#define OFF_HAS     4751360u    // 8192*4 = 32768
#define OFF_HIST    4784128u    // 256*4
#define OFF_OFFS    4785152u    // 256*4
#define OFF_SORTED  4786176u    // 8192*4 = 32768
#define OFF_CROSSP  4818944u    // 1024*4 = 4096
#define OFF_WITHINP 4823040u    // 256*4

__device__ __forceinline__ unsigned short f2bf(float f) {
    unsigned int u = __float_as_uint(f);
    unsigned int r = u + 0x7fffu + ((u >> 16) & 1u);
    return (unsigned short)(r >> 16);
}
__device__ __forceinline__ float bf2f_lo(unsigned int u) {
    return __uint_as_float(u << 16);
}
__device__ __forceinline__ float bf2f_hi(unsigned int u) {
    return __uint_as_float(u & 0xffff0000u);
}

// ---- kernel 1: row L2-normalize -> bf16 ----
__global__ __launch_bounds__(256) void k_normalize(const float* __restrict__ feat,
                                                   unsigned short* __restrict__ fnbf) {
    int wave = threadIdx.x >> 6, lane = threadIdx.x & 63;
    int row  = blockIdx.x * 4 + wave;
    const float4* src = reinterpret_cast<const float4*>(feat + (size_t)row * D_K);
    float4 v = src[lane];
    float ss = v.x * v.x + v.y * v.y + v.z * v.z + v.w * v.w;
#pragma unroll
    for (int m = 1; m < 64; m <<= 1) ss += __shfl_xor(ss, m);
    float rn = 1.0f / sqrtf(ss);
    ushort4 o;
    o.x = f2bf(v.x * rn); o.y = f2bf(v.y * rn);
    o.z = f2bf(v.z * rn); o.w = f2bf(v.w * rn);
    reinterpret_cast<ushort4*>(fnbf + (size_t)row * D_K)[lane] = o;
}

// ---- kernel 2: single-block hist + prefix + grouped scatter ----
__global__ __launch_bounds__(256) void k_prep(const int* __restrict__ lab,
                                              int* __restrict__ hist,
                                              int* __restrict__ offs,
                                              int* __restrict__ sorted) {
    __shared__ int sh_hist[256], sh_scan[256], sh_cur[256];
    int t = threadIdx.x;
    sh_hist[t] = 0;
    __syncthreads();
    for (int i = t; i < B_N; i += 256) {
        int lb = lab[i];
        if (lb >= 0 && lb < NGENE) atomicAdd(&sh_hist[lb], 1);
    }
    __syncthreads();
    int v = sh_hist[t];
    sh_scan[t] = v;
    __syncthreads();
#pragma unroll
    for (int d = 1; d < 256; d <<= 1) {
        int x = (t >= d) ? sh_scan[t - d] : 0;
        __syncthreads();
        sh_scan[t] += x;
        __syncthreads();
    }
    int excl = sh_scan[t] - v;
    sh_cur[t] = excl;
    if (t < NGENE) { hist[t] = v; offs[t] = excl; }
    __syncthreads();
    for (int i = t; i < B_N; i += 256) {
        int lb = lab[i];
        if (lb >= 0 && lb < NGENE) {
            int pos = atomicAdd(&sh_cur[lb], 1);
            sorted[pos] = i;
        }
    }
}

// asm-pinned A-fragment load: compiler cannot rematerialize, so the
// fragment STAYS in VGPRs across the whole j-sweep.
#define LOAD_A_SET(arr, base)                                                        \
    asm volatile("global_load_dwordx4 %0, %1, off offset:0"   : "=v"(arr[0]) : "v"(base)); \
    asm volatile("global_load_dwordx4 %0, %1, off offset:64"  : "=v"(arr[1]) : "v"(base)); \
    asm volatile("global_load_dwordx4 %0, %1, off offset:128" : "=v"(arr[2]) : "v"(base)); \
    asm volatile("global_load_dwordx4 %0, %1, off offset:192" : "=v"(arr[3]) : "v"(base)); \
    asm volatile("global_load_dwordx4 %0, %1, off offset:256" : "=v"(arr[4]) : "v"(base)); \
    asm volatile("global_load_dwordx4 %0, %1, off offset:320" : "=v"(arr[5]) : "v"(base)); \
    asm volatile("global_load_dwordx4 %0, %1, off offset:384" : "=v"(arr[6]) : "v"(base)); \
    asm volatile("global_load_dwordx4 %0, %1, off offset:448" : "=v"(arr[7]) : "v"(base))

// ---- kernel 3: fused pairwise pass ----
// wave = 32 rows (MT=2 row tiles), block = 4 waves = 128 rows, sweeping 512 cols
#define MT 2
__global__ __launch_bounds__(256, 2) void k_pairwise(const unsigned short* __restrict__ fnbf,
                                                     const int* __restrict__ lab,
                                                     float* __restrict__ l_part,
                                                     float* __restrict__ cross_part) {
    int wave = threadIdx.x >> 6, lane = threadIdx.x & 63;
    int g16 = lane >> 4, l16 = lane & 15;
    int r0 = blockIdx.x * 128 + wave * 32;
    int j0base = blockIdx.y * 512;

    const bf16x8* fv = reinterpret_cast<const bf16x8*>(fnbf);

    // A fragments pinned in VGPRs: 2 tiles x 8 k-slices = 64 VGPRs
    bf16x8 a0[8], a1[8];
    {
        const unsigned short* base0 = fnbf + (size_t)(r0 + l16) * D_K + g16 * 8;
        const unsigned short* base1 = base0 + 16 * D_K;
        LOAD_A_SET(a0, base0);
        LOAD_A_SET(a1, base1);
    }
    asm volatile("s_waitcnt vmcnt(0)" ::: "memory");
    __builtin_amdgcn_sched_barrier(0);

    int rl[MT][4];
#pragma unroll
    for (int t = 0; t < MT; ++t)
#pragma unroll
        for (int r = 0; r < 4; ++r)
            rl[t][r] = lab[r0 + t * 16 + g16 * 4 + r];

    float lsum[MT][4];
#pragma unroll
    for (int t = 0; t < MT; ++t)
#pragma unroll
        for (int r = 0; r < 4; ++r) lsum[t][r] = 0.f;
    float csum = 0.f;

    const bf16x8* pb = fv + (size_t)(j0base + l16) * 32 + g16;
    const int* pl = lab + j0base + l16;

    // prefetch step-0 B fragments
    bf16x8 b[8];
#pragma unroll
    for (int ks = 0; ks < 8; ++ks) b[ks] = pb[ks * 4];
    int cl = *pl;

    const float C1 = 2.885390082f;  // 2*log2(e)

#pragma unroll 2
    for (int step = 0; step < 32; ++step) {
        // prefetch next-step B while computing current
        bf16x8 bn[8];
        int cln = 0;
        if (step < 31) {
            const bf16x8* pbn = pb + 16 * 32;
#pragma unroll
            for (int ks = 0; ks < 8; ++ks) bn[ks] = pbn[ks * 4];
            cln = pl[16];
        }
        pb += 16 * 32;
        pl += 16;

        f32x4 acc0 = (f32x4){0.f, 0.f, 0.f, 0.f};
        f32x4 acc1 = (f32x4){0.f, 0.f, 0.f, 0.f};
#pragma unroll
        for (int ks = 0; ks < 8; ++ks) {
            acc0 = __builtin_amdgcn_mfma_f32_16x16x32_bf16(a0[ks], b[ks], acc0, 0, 0, 0);
            acc1 = __builtin_amdgcn_mfma_f32_16x16x32_bf16(a1[ks], b[ks], acc1, 0, 0, 0);
        }

#pragma unroll
        for (int r = 0; r < 4; ++r) {
            float av = acc0[r];
            bool neg = (rl[0][r] != cl);
            float e = exp2f(av * C1);
            float cr = fmaxf(fmaf(2.0f, av, -0.1f), 0.0f);
            lsum[0][r] += neg ? e : 0.0f;
            csum       += neg ? cr : 0.0f;
        }
#pragma unroll
        for (int r = 0; r < 4; ++r) {
            float av = acc1[r];
            bool neg = (rl[1][r] != cl);
            float e = exp2f(av * C1);
            float cr = fmaxf(fmaf(2.0f, av, -0.1f), 0.0f);
            lsum[1][r] += neg ? e : 0.0f;
            csum       += neg ? cr : 0.0f;
        }

#pragma unroll
        for (int ks = 0; ks < 8; ++ks) b[ks] = bn[ks];
        cl = cln;
    }

    // reduce masked-exp sums across the 16 lanes sharing each row
#pragma unroll
    for (int t = 0; t < MT; ++t)
#pragma unroll
        for (int r = 0; r < 4; ++r) {
            float v = lsum[t][r];
            v += __shfl_xor(v, 1); v += __shfl_xor(v, 2);
            v += __shfl_xor(v, 4); v += __shfl_xor(v, 8);
            if (l16 == 0)
                l_part[blockIdx.y * B_N + r0 + t * 16 + g16 * 4 + r] = v;
        }

    // block-reduce cross sum -> 1 value per block
    float c = csum;
#pragma unroll
    for (int m = 1; m < 64; m <<= 1) c += __shfl_xor(c, m);
    __shared__ float shc[4];
    if (lane == 0) shc[wave] = c;
    __syncthreads();
    if (threadIdx.x == 0)
        cross_part[blockIdx.y * gridDim.x + blockIdx.x] = shc[0] + shc[1] + shc[2] + shc[3];
}

// ---- kernel 4: per-gene lse combine + within-gene pair loss ----
__global__ __launch_bounds__(256) void k_within(const unsigned short* __restrict__ fnbf,
                                                const int* __restrict__ hist,
                                                const int* __restrict__ offs,
                                                const int* __restrict__ sorted,
                                                const float* __restrict__ l_part,
                                                float* __restrict__ lse,
                                                int* __restrict__ has,
                                                float* __restrict__ within_part) {
    int g = blockIdx.x;
    int n = hist[g], start = offs[g];
    int t = threadIdx.x;

    // phase 1: lse for this gene's rows
    for (int idx = t; idx < n; idx += 256) {
        int row = sorted[start + idx];
        float s = 0.f;
#pragma unroll
        for (int c = 0; c < 16; ++c) s += l_part[c * B_N + row];
        int h = (s > 0.f) ? 1 : 0;
        lse[row] = h ? logf(s) : 0.f;
        has[row] = h;
    }
    __syncthreads();

    // phase 2: unordered same-gene pairs
    float sum = 0.f;
    int nn = n * n;
    const uint4* fu = reinterpret_cast<const uint4*>(fnbf);
    for (int p = t; p < nn; p += 256) {
        int aa = p / n, bb = p - aa * n;
        if (bb <= aa) continue;
        int i = sorted[start + aa], j = sorted[start + bb];
        int anchor = i < j ? i : j;
        int other  = i < j ? j : i;
        if (!has[anchor]) continue;
        const uint4* pa = fu + (size_t)anchor * 16;
        const uint4* pb = fu + (size_t)other * 16;
        float d = 0.f;
#pragma unroll
        for (int k = 0; k < 16; ++k) {
            uint4 ua = pa[k], ub = pb[k];
            d = fmaf(bf2f_lo(ua.x), bf2f_lo(ub.x), d);
            d = fmaf(bf2f_hi(ua.x), bf2f_hi(ub.x), d);
            d = fmaf(bf2f_lo(ua.y), bf2f_lo(ub.y), d);
            d = fmaf(bf2f_hi(ua.y), bf2f_hi(ub.y), d);
            d = fmaf(bf2f_lo(ua.z), bf2f_lo(ub.z), d);
            d = fmaf(bf2f_hi(ua.z), bf2f_hi(ub.z), d);
            d = fmaf(bf2f_lo(ua.w), bf2f_lo(ub.w), d);
            d = fmaf(bf2f_hi(ua.w), bf2f_hi(ub.w), d);
        }
        float x = lse[anchor] - 2.0f * d;
        sum += fmaxf(x, 0.f) + log1pf(__expf(-fabsf(x)));
    }
    __shared__ float sh[256];
    sh[t] = sum;
    __syncthreads();
#pragma unroll
    for (int d2 = 128; d2 > 0; d2 >>= 1) {
        if (t < d2) sh[t] += sh[t + d2];
        __syncthreads();
    }
    if (t == 0) within_part[g] = sh[0];
}

// ---- kernel 5: final reduction + outputs ----
__global__ __launch_bounds__(256) void k_finalize(const float* __restrict__ cross_part,
                                                  const float* __restrict__ within_part,
                                                  const int* __restrict__ hist,
                                                  float* __restrict__ out) {
    __shared__ float shc[256];
    __shared__ float shw[256];
    __shared__ long long shs[256];
    int t = threadIdx.x;
    float cs = 0.f;
    for (int i = t; i < 1024; i += 256) cs += cross_part[i];
    float wv = (t < NGENE) ? within_part[t] : 0.f;
    long long s2 = 0;
    if (t < NGENE) { long long h = hist[t]; s2 = h * h; }
    shc[t] = cs; shw[t] = wv; shs[t] = s2;
    __syncthreads();
#pragma unroll
    for (int d = 128; d > 0; d >>= 1) {
        if (t < d) { shc[t] += shc[t + d]; shw[t] += shw[t + d]; shs[t] += shs[t + d]; }
        __syncthreads();
    }
    if (t == 0) {
        long long S  = shs[0];
        long long nw = S - (long long)B_N;
        long long nc = (long long)B_N * (long long)B_N - S;
        float cross_loss = (nc > 0) ? (shc[0] / (float)(nc > 1 ? nc : 1)) : 0.f;
        float within     = shw[0];
        float total      = within + 0.5f * cross_loss;
        out[0] = total;
        out[1] = within;
        out[2] = cross_loss;
        out[3] = (float)nw;
        out[4] = (float)nc;
    }
}

extern "C" void kernel_launch(void* const* d_in, const int* in_sizes, int n_in,
                              void* d_out, int out_size, void* d_ws, size_t ws_size,
                              hipStream_t stream) {
    const float* feat = (const float*)d_in[0];
    const int*   lab  = (const int*)d_in[1];
    float* out = (float*)d_out;
    char* ws = (char*)d_ws;

    unsigned short* fnbf = (unsigned short*)(ws + OFF_FNBF);
    float* l_part        = (float*)(ws + OFF_LPART);
    float* lse           = (float*)(ws + OFF_LSE);
    int*   has           = (int*)(ws + OFF_HAS);
    int*   hist          = (int*)(ws + OFF_HIST);
    int*   offs          = (int*)(ws + OFF_OFFS);
    int*   sorted        = (int*)(ws + OFF_SORTED);
    float* cross_part    = (float*)(ws + OFF_CROSSP);
    float* within_part   = (float*)(ws + OFF_WITHINP);

    k_normalize<<<B_N / 4, 256, 0, stream>>>(feat, fnbf);
    k_prep<<<1, 256, 0, stream>>>(lab, hist, offs, sorted);
    k_pairwise<<<dim3(B_N / 128, 16), 256, 0, stream>>>(fnbf, lab, l_part, cross_part);
    k_within<<<NGENE, 256, 0, stream>>>(fnbf, hist, offs, sorted, l_part, lse, has, within_part);
    k_finalize<<<1, 256, 0, stream>>>(cross_part, within_part, hist, out);
}

// Round 4
// 147.311 us; speedup vs baseline: 1.2981x; 1.2981x over previous
//
#include <hip/hip_runtime.h>
#include <math.h>

#define B_N   8192
#define D_K   256
#define NGENE 200
#define MAXN  512

typedef short  bf16x8 __attribute__((ext_vector_type(8)));
typedef float  f32x4  __attribute__((ext_vector_type(4)));

// ---- workspace layout (bytes), total 4,757,504 ----
#define OFF_FNBF    0u          // 8192*256*2 = 4194304
#define OFF_LPART   4194304u    // 16*8192*4  = 524288
#define OFF_HIST    4718592u    // 256*4
#define OFF_OFFS    4719616u    // 256*4
#define OFF_SORTED  4720640u    // 8192*4
#define OFF_CROSSP  4753408u    // 512*4
#define OFF_WITHINP 4755456u    // 256*4
#define OFF_CCORR   4756480u    // 256*4

__device__ __forceinline__ unsigned short f2bf(float f) {
    unsigned int u = __float_as_uint(f);
    unsigned int r = u + 0x7fffu + ((u >> 16) & 1u);
    return (unsigned short)(r >> 16);
}
__device__ __forceinline__ float bf2f_lo(unsigned int u) { return __uint_as_float(u << 16); }
__device__ __forceinline__ float bf2f_hi(unsigned int u) { return __uint_as_float(u & 0xffff0000u); }

// ---- kernel 1: row L2-normalize -> bf16 ----
__global__ __launch_bounds__(256) void k_normalize(const float* __restrict__ feat,
                                                   unsigned short* __restrict__ fnbf) {
    int wave = threadIdx.x >> 6, lane = threadIdx.x & 63;
    int row  = blockIdx.x * 4 + wave;
    const float4* src = reinterpret_cast<const float4*>(feat + (size_t)row * D_K);
    float4 v = src[lane];
    float ss = v.x * v.x + v.y * v.y + v.z * v.z + v.w * v.w;
#pragma unroll
    for (int m = 1; m < 64; m <<= 1) ss += __shfl_xor(ss, m);
    float rn = 1.0f / sqrtf(ss);
    ushort4 o;
    o.x = f2bf(v.x * rn); o.y = f2bf(v.y * rn);
    o.z = f2bf(v.z * rn); o.w = f2bf(v.w * rn);
    reinterpret_cast<ushort4*>(fnbf + (size_t)row * D_K)[lane] = o;
}

// ---- kernel 2: single-block hist + prefix + grouped scatter ----
__global__ __launch_bounds__(256) void k_prep(const int* __restrict__ lab,
                                              int* __restrict__ hist,
                                              int* __restrict__ offs,
                                              int* __restrict__ sorted) {
    __shared__ int sh_hist[256], sh_scan[256], sh_cur[256];
    int t = threadIdx.x;
    sh_hist[t] = 0;
    __syncthreads();
    for (int i = t; i < B_N; i += 256) {
        int lb = lab[i];
        if (lb >= 0 && lb < NGENE) atomicAdd(&sh_hist[lb], 1);
    }
    __syncthreads();
    int v = sh_hist[t];
    sh_scan[t] = v;
    __syncthreads();
#pragma unroll
    for (int d = 1; d < 256; d <<= 1) {
        int x = (t >= d) ? sh_scan[t - d] : 0;
        __syncthreads();
        sh_scan[t] += x;
        __syncthreads();
    }
    int excl = sh_scan[t] - v;
    sh_cur[t] = excl;
    if (t < NGENE) { hist[t] = v; offs[t] = excl; }
    __syncthreads();
    for (int i = t; i < B_N; i += 256) {
        int lb = lab[i];
        if (lb >= 0 && lb < NGENE) {
            int pos = atomicAdd(&sh_cur[lb], 1);
            sorted[pos] = i;
        }
    }
}

// 8 x 16B saddr-form loads: SGPR base + 32-bit voffset, ks*64 as immediate
#define GLOAD8(buf, vo) do {                                                                   \
    asm volatile("global_load_dwordx4 %0, %1, %2 offset:0"   : "=v"(buf[0]) : "v"(vo), "s"(fb)); \
    asm volatile("global_load_dwordx4 %0, %1, %2 offset:64"  : "=v"(buf[1]) : "v"(vo), "s"(fb)); \
    asm volatile("global_load_dwordx4 %0, %1, %2 offset:128" : "=v"(buf[2]) : "v"(vo), "s"(fb)); \
    asm volatile("global_load_dwordx4 %0, %1, %2 offset:192" : "=v"(buf[3]) : "v"(vo), "s"(fb)); \
    asm volatile("global_load_dwordx4 %0, %1, %2 offset:256" : "=v"(buf[4]) : "v"(vo), "s"(fb)); \
    asm volatile("global_load_dwordx4 %0, %1, %2 offset:320" : "=v"(buf[5]) : "v"(vo), "s"(fb)); \
    asm volatile("global_load_dwordx4 %0, %1, %2 offset:384" : "=v"(buf[6]) : "v"(vo), "s"(fb)); \
    asm volatile("global_load_dwordx4 %0, %1, %2 offset:448" : "=v"(buf[7]) : "v"(vo), "s"(fb)); \
} while (0)

#define WAIT_VM(n) do { asm volatile("s_waitcnt vmcnt(" #n ")" ::: "memory"); \
                        __builtin_amdgcn_sched_barrier(0); } while (0)

#define STEP_MFMA(buf)                                                                \
    f32x4 acc0 = (f32x4){0.f,0.f,0.f,0.f}, acc1 = acc0, acc2 = acc0, acc3 = acc0;     \
    _Pragma("unroll")                                                                 \
    for (int ks = 0; ks < 8; ++ks) {                                                  \
        acc0 = __builtin_amdgcn_mfma_f32_16x16x32_bf16(a0[ks], buf[ks], acc0, 0,0,0); \
        acc1 = __builtin_amdgcn_mfma_f32_16x16x32_bf16(a1[ks], buf[ks], acc1, 0,0,0); \
        acc2 = __builtin_amdgcn_mfma_f32_16x16x32_bf16(a2[ks], buf[ks], acc2, 0,0,0); \
        acc3 = __builtin_amdgcn_mfma_f32_16x16x32_bf16(a3[ks], buf[ks], acc3, 0,0,0); \
    }

#define STEP_EPIL                                                   \
    _Pragma("unroll")                                               \
    for (int r = 0; r < 4; ++r) {                                   \
        ls0[r] += __expf(2.0f * acc0[r]);                           \
        ls1[r] += __expf(2.0f * acc1[r]);                           \
        ls2[r] += __expf(2.0f * acc2[r]);                           \
        ls3[r] += __expf(2.0f * acc3[r]);                           \
        csum += fmaxf(acc0[r] - 0.05f, 0.f);                        \
        csum += fmaxf(acc1[r] - 0.05f, 0.f);                        \
        csum += fmaxf(acc2[r] - 0.05f, 0.f);                        \
        csum += fmaxf(acc3[r] - 0.05f, 0.f);                        \
    }

// ---- kernel 3: fused pairwise pass (UNMASKED sums; corrections in k_within) ----
// block = 4 waves x 64 rows = 256 rows; all waves share one 512-col window (L1 dedupe)
__global__ __launch_bounds__(256, 2) void k_pairwise(const unsigned short* __restrict__ fnbf,
                                                     float* __restrict__ l_part,
                                                     float* __restrict__ cross_part) {
    int wave = threadIdx.x >> 6, lane = threadIdx.x & 63;
    int g16 = lane >> 4, l16 = lane & 15;
    int rg = blockIdx.x, cw = blockIdx.y;
    int r0 = rg * 256 + wave * 64;
    const unsigned short* fb = fnbf;

    // A fragments: 4 row-tiles x 8 k-slices = 128 VGPRs, asm-pinned
    bf16x8 a0[8], a1[8], a2[8], a3[8];
    unsigned voa = (unsigned)(r0 + l16) * 512u + (unsigned)g16 * 16u;
    GLOAD8(a0, voa); voa += 16u * 512u;
    GLOAD8(a1, voa); voa += 16u * 512u;
    GLOAD8(a2, voa); voa += 16u * 512u;
    GLOAD8(a3, voa);

    // B ping-pong prologue: steps 0 and 1
    bf16x8 b0[8], b1[8];
    unsigned vob = (unsigned)(cw * 512 + l16) * 512u + (unsigned)g16 * 16u;
    GLOAD8(b0, vob); vob += 8192u;
    GLOAD8(b1, vob); vob += 8192u;

    WAIT_VM(16);  // A fragments ready; b0,b1 (16 loads) still in flight

    float ls0[4] = {0,0,0,0}, ls1[4] = {0,0,0,0}, ls2[4] = {0,0,0,0}, ls3[4] = {0,0,0,0};
    float csum = 0.f;

#pragma unroll 1
    for (int it = 0; it < 15; ++it) {
        {
            WAIT_VM(8);                      // b0 ready (b1's 8 in flight)
            STEP_MFMA(b0);
            GLOAD8(b0, vob); vob += 8192u;   // prefetch step 2it+2
            STEP_EPIL;
        }
        {
            WAIT_VM(8);                      // b1 ready (b0's 8 in flight)
            STEP_MFMA(b1);
            GLOAD8(b1, vob); vob += 8192u;   // prefetch step 2it+3
            STEP_EPIL;
        }
    }
    {   // step 30
        WAIT_VM(8);
        STEP_MFMA(b0);
        STEP_EPIL;
    }
    {   // step 31
        WAIT_VM(0);
        STEP_MFMA(b1);
        STEP_EPIL;
    }

    // reduce exp-sums across the 16 lanes sharing each output row
#pragma unroll
    for (int tr = 0; tr < 4; ++tr) {
#pragma unroll
        for (int r = 0; r < 4; ++r) {
            float v = (tr == 0) ? ls0[r] : (tr == 1) ? ls1[r] : (tr == 2) ? ls2[r] : ls3[r];
            v += __shfl_xor(v, 1); v += __shfl_xor(v, 2);
            v += __shfl_xor(v, 4); v += __shfl_xor(v, 8);
            if (l16 == 0)
                l_part[cw * B_N + r0 + tr * 16 + g16 * 4 + r] = v;
        }
    }

    // block-reduce half-relu sum
    float c = csum;
#pragma unroll
    for (int m = 1; m < 64; m <<= 1) c += __shfl_xor(c, m);
    __shared__ float shc[4];
    if (lane == 0) shc[wave] = c;
    __syncthreads();
    if (threadIdx.x == 0)
        cross_part[cw * 32 + rg] = shc[0] + shc[1] + shc[2] + shc[3];
}

__device__ __forceinline__ float dot_rows(const uint4* __restrict__ fu, int i, int j) {
    const uint4* pa = fu + (size_t)i * 16;
    const uint4* pb = fu + (size_t)j * 16;
    float d = 0.f;
#pragma unroll
    for (int k = 0; k < 16; ++k) {
        uint4 ua = pa[k], ub = pb[k];
        d = fmaf(bf2f_lo(ua.x), bf2f_lo(ub.x), d);
        d = fmaf(bf2f_hi(ua.x), bf2f_hi(ub.x), d);
        d = fmaf(bf2f_lo(ua.y), bf2f_lo(ub.y), d);
        d = fmaf(bf2f_hi(ua.y), bf2f_hi(ub.y), d);
        d = fmaf(bf2f_lo(ua.z), bf2f_lo(ub.z), d);
        d = fmaf(bf2f_hi(ua.z), bf2f_hi(ub.z), d);
        d = fmaf(bf2f_lo(ua.w), bf2f_lo(ub.w), d);
        d = fmaf(bf2f_hi(ua.w), bf2f_hi(ub.w), d);
    }
    return d;
}

// ---- kernel 4: per-gene corrections + lse + within-gene loss ----
__global__ __launch_bounds__(256) void k_within(const unsigned short* __restrict__ fnbf,
                                                const int* __restrict__ hist,
                                                const int* __restrict__ offs,
                                                const int* __restrict__ sorted,
                                                const float* __restrict__ l_part,
                                                float* __restrict__ within_part,
                                                float* __restrict__ cross_corr) {
    int g = blockIdx.x;
    int n = hist[g], start = offs[g];
    int t = threadIdx.x;
    __shared__ int   rid[MAXN];
    __shared__ float rexp[MAXN];
    __shared__ float slse[MAXN];
    __shared__ float red[256];

    const uint4* fu = reinterpret_cast<const uint4*>(fnbf);
    float ccor = 0.f;

    // phase 1: raw exp-sum, minus diagonal; diag cross correction
    for (int idx = t; idx < n; idx += 256) {
        int row = sorted[start + idx];
        rid[idx] = row;
        float raw = 0.f;
#pragma unroll
        for (int c = 0; c < 16; ++c) raw += l_part[c * B_N + row];
        float ss = dot_rows(fu, row, row);
        float dexp = __expf(2.0f * ss);
        ccor += fmaxf(2.0f * ss - 0.1f, 0.f);
        rexp[idx] = raw - dexp;
    }
    __syncthreads();

    int P = n * (n - 1) / 2;

    // phase A: subtract same-gene pair exps; accumulate cross correction
    for (int p = t; p < P; p += 256) {
        int aa = 0, pp = p, span = n - 1;
        while (pp >= span) { pp -= span; ++aa; --span; }
        int bb = aa + 1 + pp;
        float s = 2.0f * dot_rows(fu, rid[aa], rid[bb]);
        float e = __expf(s);
        atomicAdd(&rexp[aa], -e);
        atomicAdd(&rexp[bb], -e);
        ccor += 2.0f * fmaxf(s - 0.1f, 0.f);
    }
    __syncthreads();

    // phase B: lse per row (every row has negatives: B_N - n > 0)
    for (int idx = t; idx < n; idx += 256)
        slse[idx] = __logf(rexp[idx]);
    __syncthreads();

    // phase 2: softplus over pairs, anchor = smaller row index
    float wsum = 0.f;
    for (int p = t; p < P; p += 256) {
        int aa = 0, pp = p, span = n - 1;
        while (pp >= span) { pp -= span; ++aa; --span; }
        int bb = aa + 1 + pp;
        int ia = rid[aa], ib = rid[bb];
        float s = 2.0f * dot_rows(fu, ia, ib);
        int ai = (ia < ib) ? aa : bb;
        float x = slse[ai] - s;
        wsum += fmaxf(x, 0.f) + log1pf(__expf(-fabsf(x)));
    }

    red[t] = wsum;
    __syncthreads();
#pragma unroll
    for (int d = 128; d > 0; d >>= 1) {
        if (t < d) red[t] += red[t + d];
        __syncthreads();
    }
    if (t == 0) within_part[g] = red[0];
    __syncthreads();
    red[t] = ccor;
    __syncthreads();
#pragma unroll
    for (int d = 128; d > 0; d >>= 1) {
        if (t < d) red[t] += red[t + d];
        __syncthreads();
    }
    if (t == 0) cross_corr[g] = red[0];
}

// ---- kernel 5: final reduction + outputs ----
__global__ __launch_bounds__(256) void k_finalize(const float* __restrict__ cross_part,
                                                  const float* __restrict__ within_part,
                                                  const float* __restrict__ cross_corr,
                                                  const int* __restrict__ hist,
                                                  float* __restrict__ out) {
    __shared__ float shc[256];
    __shared__ float shw[256];
    __shared__ float shk[256];
    __shared__ long long shs[256];
    int t = threadIdx.x;
    float cs = 0.f;
    for (int i = t; i < 512; i += 256) cs += cross_part[i];
    float wv = 0.f, cc = 0.f;
    long long s2 = 0;
    if (t < NGENE) {
        wv = within_part[t];
        cc = cross_corr[t];
        long long h = hist[t];
        s2 = h * h;
    }
    shc[t] = cs; shw[t] = wv; shk[t] = cc; shs[t] = s2;
    __syncthreads();
#pragma unroll
    for (int d = 128; d > 0; d >>= 1) {
        if (t < d) {
            shc[t] += shc[t + d]; shw[t] += shw[t + d];
            shk[t] += shk[t + d]; shs[t] += shs[t + d];
        }
        __syncthreads();
    }
    if (t == 0) {
        long long S  = shs[0];
        long long nw = S - (long long)B_N;
        long long nc = (long long)B_N * (long long)B_N - S;
        float cross_total = 2.0f * shc[0] - shk[0];   // csum was half-relu units
        float cross_loss = (nc > 0) ? (cross_total / (float)(nc > 1 ? nc : 1)) : 0.f;
        float within     = shw[0];
        out[0] = within + 0.5f * cross_loss;
        out[1] = within;
        out[2] = cross_loss;
        out[3] = (float)nw;
        out[4] = (float)nc;
    }
}

extern "C" void kernel_launch(void* const* d_in, const int* in_sizes, int n_in,
                              void* d_out, int out_size, void* d_ws, size_t ws_size,
                              hipStream_t stream) {
    const float* feat = (const float*)d_in[0];
    const int*   lab  = (const int*)d_in[1];
    float* out = (float*)d_out;
    char* ws = (char*)d_ws;

    unsigned short* fnbf = (unsigned short*)(ws + OFF_FNBF);
    float* l_part        = (float*)(ws + OFF_LPART);
    int*   hist          = (int*)(ws + OFF_HIST);
    int*   offs          = (int*)(ws + OFF_OFFS);
    int*   sorted        = (int*)(ws + OFF_SORTED);
    float* cross_part    = (float*)(ws + OFF_CROSSP);
    float* within_part   = (float*)(ws + OFF_WITHINP);
    float* cross_corr    = (float*)(ws + OFF_CCORR);

    k_normalize<<<B_N / 4, 256, 0, stream>>>(feat, fnbf);
    k_prep<<<1, 256, 0, stream>>>(lab, hist, offs, sorted);
    k_pairwise<<<dim3(32, 16), 256, 0, stream>>>(fnbf, l_part, cross_part);
    k_within<<<NGENE, 256, 0, stream>>>(fnbf, hist, offs, sorted, l_part, within_part, cross_corr);
    k_finalize<<<1, 256, 0, stream>>>(cross_part, within_part, cross_corr, hist, out);
}